// Round 1
// baseline (694.656 us; speedup 1.0000x reference)
//
#include <hip/hip_runtime.h>
#include <hip/hip_bf16.h>

// Segment mean: data [TOTAL_POINTS, 128] fp32, obj_size [N_SEG] int32,
// out [N_SEG, 128] fp32.  out[s, :] = mean(data[start_s : start_s+cnt_s, :], 0)
// where start_s = exclusive cumsum of obj_size.

#define D_FEAT 128
#define FEAT_QUADS (D_FEAT / 4)   // 32 float4 per row

// ---------------------------------------------------------------------------
// Kernel 1: exclusive prefix sum of obj_size -> offsets (single block).
// n_seg up to 1024*ITEMS handled; 16384 -> 16 items/thread.
// ---------------------------------------------------------------------------
__global__ __launch_bounds__(1024) void seg_scan_kernel(
    const int* __restrict__ obj_size, int* __restrict__ offsets, int n_seg) {
  __shared__ int smem[1024];
  const int T = 1024;
  const int tid = threadIdx.x;
  const int per = (n_seg + T - 1) / T;
  const int begin = tid * per;
  const int end = (begin + per < n_seg) ? (begin + per) : n_seg;

  int local = 0;
  for (int i = begin; i < end; ++i) local += obj_size[i];
  smem[tid] = local;
  __syncthreads();

  // Hillis–Steele inclusive scan over thread sums.
  for (int off = 1; off < T; off <<= 1) {
    int v = 0;
    if (tid >= off) v = smem[tid - off];
    __syncthreads();
    if (tid >= off) smem[tid] += v;
    __syncthreads();
  }

  int excl = (tid == 0) ? 0 : smem[tid - 1];
  for (int i = begin; i < end; ++i) {
    offsets[i] = excl;
    excl += obj_size[i];
  }
}

// ---------------------------------------------------------------------------
// Kernel 2: one block per segment. 256 threads = 32 feature-quads x 8 rows.
// ---------------------------------------------------------------------------
__global__ __launch_bounds__(256) void seg_mean_kernel(
    const float* __restrict__ data, const int* __restrict__ obj_size,
    const int* __restrict__ offsets, float* __restrict__ out, int n_seg) {
  const int seg = blockIdx.x;
  if (seg >= n_seg) return;

  const int start = offsets[seg];
  const int count = obj_size[seg];

  const int tid = threadIdx.x;
  const int lane_f = tid & 31;  // which float4 of the row (feature quad)
  const int rp = tid >> 5;      // 0..7 parallel-row group

  const float4* __restrict__ base = (const float4*)data;

  float4 acc = make_float4(0.f, 0.f, 0.f, 0.f);
  for (int r = rp; r < count; r += 8) {
    float4 v = base[(size_t)(start + r) * FEAT_QUADS + lane_f];
    acc.x += v.x; acc.y += v.y; acc.z += v.z; acc.w += v.w;
  }

  __shared__ float4 smem[256];
  smem[tid] = acc;
  __syncthreads();

  // Tree reduce across the 8 row groups.
  for (int s = 4; s >= 1; s >>= 1) {
    if (rp < s) {
      float4 o = smem[tid + s * 32];
      acc.x += o.x; acc.y += o.y; acc.z += o.z; acc.w += o.w;
      smem[tid] = acc;
    }
    __syncthreads();
  }

  if (rp == 0) {
    const float inv = (count > 0) ? (1.0f / (float)count) : 0.0f;
    float4 r = make_float4(acc.x * inv, acc.y * inv, acc.z * inv, acc.w * inv);
    ((float4*)out)[(size_t)seg * FEAT_QUADS + lane_f] = r;
  }
}

extern "C" void kernel_launch(void* const* d_in, const int* in_sizes, int n_in,
                              void* d_out, int out_size, void* d_ws, size_t ws_size,
                              hipStream_t stream) {
  const float* data = (const float*)d_in[0];
  const int* obj_size = (const int*)d_in[1];
  const int n_seg = in_sizes[1];
  float* out = (float*)d_out;
  int* offsets = (int*)d_ws;  // n_seg ints of scratch

  seg_scan_kernel<<<1, 1024, 0, stream>>>(obj_size, offsets, n_seg);
  seg_mean_kernel<<<n_seg, 256, 0, stream>>>(data, obj_size, offsets, out, n_seg);
}

// Round 2
// 676.967 us; speedup vs baseline: 1.0261x; 1.0261x over previous
//
#include <hip/hip_runtime.h>
#include <hip/hip_bf16.h>

// Segment mean: data [TOTAL_POINTS, 128] fp32, obj_size [N_SEG] int32,
// out [N_SEG, 128] fp32.  out[s, :] = mean(data[start_s : start_s+cnt_s, :], 0)
// start_s = exclusive cumsum of obj_size (computed in d_ws by kernel 1).

#define D_FEAT 128
#define FEAT_QUADS (D_FEAT / 4)   // 32 float4 per row (512 B per row)

typedef float v4f __attribute__((ext_vector_type(4)));

// ---------------------------------------------------------------------------
// Kernel 1: exclusive prefix sum of obj_size -> offsets (single block,
// wave-shuffle scan: 2 barriers instead of 20).
// ---------------------------------------------------------------------------
__global__ __launch_bounds__(1024) void seg_scan_kernel(
    const int* __restrict__ obj_size, int* __restrict__ offsets, int n_seg) {
  const int T = 1024;
  const int tid = threadIdx.x;
  const int lane = tid & 63;
  const int wid = tid >> 6;  // 0..15
  const int per = (n_seg + T - 1) / T;
  const int begin = tid * per;
  const int end = (begin + per < n_seg) ? (begin + per) : n_seg;

  int local = 0;
  for (int i = begin; i < end; ++i) local += obj_size[i];

  // Inclusive wave scan of per-thread sums.
  int x = local;
  #pragma unroll
  for (int off = 1; off < 64; off <<= 1) {
    int y = __shfl_up(x, off, 64);
    if (lane >= off) x += y;
  }

  __shared__ int wsum[16];
  if (lane == 63) wsum[wid] = x;
  __syncthreads();
  if (tid < 16) {
    int w = wsum[tid];
    #pragma unroll
    for (int off = 1; off < 16; off <<= 1) {
      int y = __shfl_up(w, off, 64);
      if (tid >= off) w += y;
    }
    wsum[tid] = w;  // inclusive scan of wave totals
  }
  __syncthreads();

  // Exclusive prefix for this thread's first element.
  int excl = (wid > 0 ? wsum[wid - 1] : 0) + (x - local);
  for (int i = begin; i < end; ++i) {
    offsets[i] = excl;
    excl += obj_size[i];
  }
}

// ---------------------------------------------------------------------------
// Kernel 2: one WAVE per segment (no LDS, no barriers).
// 64 lanes = 2 rows x 32 feature-quads; cross-half reduce via shfl_xor(32).
// Block 256 = 4 waves = 4 segments.
// ---------------------------------------------------------------------------
__global__ __launch_bounds__(256) void seg_mean_kernel(
    const float* __restrict__ data, const int* __restrict__ obj_size,
    const int* __restrict__ offsets, float* __restrict__ out, int n_seg) {
  const int tid = threadIdx.x;
  const int wid = tid >> 6;
  const int lane = tid & 63;
  const int seg = blockIdx.x * 4 + wid;
  if (seg >= n_seg) return;

  const int start = offsets[seg];
  const int count = obj_size[seg];

  const int lane_f = lane & 31;  // feature quad 0..31
  const int half = lane >> 5;    // row parity 0/1

  const v4f* __restrict__ base =
      (const v4f*)data + (size_t)start * FEAT_QUADS + lane_f;

  v4f acc = (v4f)(0.0f);
  for (int r = half; r < count; r += 2) {
    v4f v = __builtin_nontemporal_load(base + (size_t)r * FEAT_QUADS);
    acc += v;
  }

  // Reduce across the two row-halves of the wave (lane L += lane L^32).
  acc.x += __shfl_xor(acc.x, 32, 64);
  acc.y += __shfl_xor(acc.y, 32, 64);
  acc.z += __shfl_xor(acc.z, 32, 64);
  acc.w += __shfl_xor(acc.w, 32, 64);

  if (half == 0) {
    const float inv = (count > 0) ? (1.0f / (float)count) : 0.0f;
    v4f r = acc * inv;
    v4f* o = (v4f*)out + (size_t)seg * FEAT_QUADS + lane_f;
    __builtin_nontemporal_store(r, o);
  }
}

extern "C" void kernel_launch(void* const* d_in, const int* in_sizes, int n_in,
                              void* d_out, int out_size, void* d_ws, size_t ws_size,
                              hipStream_t stream) {
  const float* data = (const float*)d_in[0];
  const int* obj_size = (const int*)d_in[1];
  const int n_seg = in_sizes[1];
  float* out = (float*)d_out;
  int* offsets = (int*)d_ws;  // n_seg ints of scratch

  seg_scan_kernel<<<1, 1024, 0, stream>>>(obj_size, offsets, n_seg);
  const int blocks = (n_seg + 3) / 4;  // 4 segments (waves) per block
  seg_mean_kernel<<<blocks, 256, 0, stream>>>(data, obj_size, offsets, out,
                                              n_seg);
}

// Round 3
// 667.653 us; speedup vs baseline: 1.0404x; 1.0140x over previous
//
#include <hip/hip_runtime.h>
#include <hip/hip_bf16.h>

// Segment mean: data [TOTAL_POINTS, 128] fp32, obj_size [N_SEG] int32,
// out [N_SEG, 128] fp32.  out[s, :] = mean(data[start_s : start_s+cnt_s, :], 0)
// Kernel 1 writes int2{start,count} descriptors into d_ws.

#define D_FEAT 128
#define FEAT_QUADS (D_FEAT / 4)   // 32 float4 per row (512 B per row)

typedef float v4f __attribute__((ext_vector_type(4)));

// ---------------------------------------------------------------------------
// Kernel 1: exclusive prefix sum of obj_size -> int2{start,count} descriptors.
// Single 1024-thread block, wave-shuffle scan (2 barriers).
// ---------------------------------------------------------------------------
__global__ __launch_bounds__(1024) void seg_scan_kernel(
    const int* __restrict__ obj_size, int2* __restrict__ descs, int n_seg) {
  const int T = 1024;
  const int tid = threadIdx.x;
  const int lane = tid & 63;
  const int wid = tid >> 6;  // 0..15
  const int per = (n_seg + T - 1) / T;
  const int begin = tid * per;
  const int end = (begin + per < n_seg) ? (begin + per) : n_seg;

  int local = 0;
  for (int i = begin; i < end; ++i) local += obj_size[i];

  // Inclusive wave scan of per-thread sums.
  int x = local;
  #pragma unroll
  for (int off = 1; off < 64; off <<= 1) {
    int y = __shfl_up(x, off, 64);
    if (lane >= off) x += y;
  }

  __shared__ int wsum[16];
  if (lane == 63) wsum[wid] = x;
  __syncthreads();
  if (tid < 16) {
    int w = wsum[tid];
    #pragma unroll
    for (int off = 1; off < 16; off <<= 1) {
      int y = __shfl_up(w, off, 64);
      if (tid >= off) w += y;
    }
    wsum[tid] = w;  // inclusive scan of wave totals
  }
  __syncthreads();

  int excl = (wid > 0 ? wsum[wid - 1] : 0) + (x - local);
  for (int i = begin; i < end; ++i) {
    int c = obj_size[i];
    descs[i] = make_int2(excl, c);
    excl += c;
  }
}

// ---------------------------------------------------------------------------
// Kernel 2: one WAVE per segment, no LDS/barriers.
// 64 lanes = 2 rows x 32 feature-quads. Unroll x4 => 4 loads in flight/lane.
// ---------------------------------------------------------------------------
__global__ __launch_bounds__(256) void seg_mean_kernel(
    const float* __restrict__ data, const int2* __restrict__ descs,
    float* __restrict__ out, int n_seg) {
  const int tid = threadIdx.x;
  const int wid = tid >> 6;
  const int lane = tid & 63;
  const int seg = blockIdx.x * 4 + wid;
  if (seg >= n_seg) return;

  const int2 d = descs[seg];
  const int start = d.x;
  const int count = d.y;

  const int lane_f = lane & 31;  // feature quad 0..31
  const int half = lane >> 5;    // row parity 0/1

  const v4f* __restrict__ base =
      (const v4f*)data + (size_t)start * FEAT_QUADS + lane_f;

  v4f a0 = (v4f)(0.0f), a1 = (v4f)(0.0f), a2 = (v4f)(0.0f), a3 = (v4f)(0.0f);
  int r = half;
  // 8 rows (4 loads/lane) per trip; all 4 loads independent.
  for (; r + 6 < count; r += 8) {
    v4f v0 = __builtin_nontemporal_load(base + (size_t)(r + 0) * FEAT_QUADS);
    v4f v1 = __builtin_nontemporal_load(base + (size_t)(r + 2) * FEAT_QUADS);
    v4f v2 = __builtin_nontemporal_load(base + (size_t)(r + 4) * FEAT_QUADS);
    v4f v3 = __builtin_nontemporal_load(base + (size_t)(r + 6) * FEAT_QUADS);
    a0 += v0;
    a1 += v1;
    a2 += v2;
    a3 += v3;
  }
  for (; r < count; r += 2)
    a0 += __builtin_nontemporal_load(base + (size_t)r * FEAT_QUADS);

  v4f acc = (a0 + a1) + (a2 + a3);

  // Reduce across the two row-halves of the wave.
  acc.x += __shfl_xor(acc.x, 32, 64);
  acc.y += __shfl_xor(acc.y, 32, 64);
  acc.z += __shfl_xor(acc.z, 32, 64);
  acc.w += __shfl_xor(acc.w, 32, 64);

  if (half == 0) {
    const float inv = (count > 0) ? (1.0f / (float)count) : 0.0f;
    v4f res = acc * inv;
    v4f* o = (v4f*)out + (size_t)seg * FEAT_QUADS + lane_f;
    __builtin_nontemporal_store(res, o);
  }
}

extern "C" void kernel_launch(void* const* d_in, const int* in_sizes, int n_in,
                              void* d_out, int out_size, void* d_ws, size_t ws_size,
                              hipStream_t stream) {
  const float* data = (const float*)d_in[0];
  const int* obj_size = (const int*)d_in[1];
  const int n_seg = in_sizes[1];
  float* out = (float*)d_out;
  int2* descs = (int2*)d_ws;  // n_seg int2 descriptors

  seg_scan_kernel<<<1, 1024, 0, stream>>>(obj_size, descs, n_seg);
  const int blocks = (n_seg + 3) / 4;  // 4 segments (waves) per block
  seg_mean_kernel<<<blocks, 256, 0, stream>>>(data, descs, out, n_seg);
}